// Round 4
// baseline (299.458 us; speedup 1.0000x reference)
//
#include <hip/hip_runtime.h>
#include <cstdint>
#include <cstddef>

// Problem constants (match reference setup_inputs)
#define BB 32
#define SS 4096          // 2^12
#define FEAT_ 64
#define HID_ 32
#define NN 1024          // MAX_NODES
#define RPB 8            // adjacency rows per block (dense LDS tile = 32 KB)

#define EDGE_BLOCKS ((BB * SS) / 256)   // fallback path only
#define NF_BLOCKS   ((BB * NN) / 32)

typedef int v4i __attribute__((ext_vector_type(4)));

// ---------------------------------------------------------------------------
// Edge weight from the factored MLP.
//   AB[n][0:32]  = emb[n] @ W1[0:64] + b1     (A half)
//   AB[n][32:64] = emb[n] @ W1[64:128]        (B half)
// Float expression identical to the round-1 edge phase -> bit-identical w.
// ---------------------------------------------------------------------------
__device__ __forceinline__ float edge_weight(const float* __restrict__ ab,
                                             const float* __restrict__ W2,
                                             float b2v, int src_n, int dst_n,
                                             float volv) {
    const float4* As = (const float4*)(ab + (src_n << 6));
    const float4* Bd = (const float4*)(ab + (dst_n << 6) + HID_);
    float dotv = b2v;
    #pragma unroll
    for (int q = 0; q < 8; ++q) {
        float4 a  = As[q];
        float4 bv = Bd[q];
        float4 wv = *(const float4*)(W2 + (q << 2));
        dotv += fmaxf(a.x + bv.x, 0.0f) * wv.x;
        dotv += fmaxf(a.y + bv.y, 0.0f) * wv.y;
        dotv += fmaxf(a.z + bv.z, 0.0f) * wv.z;
        dotv += fmaxf(a.w + bv.w, 0.0f) * wv.w;
    }
    float edge_w = 1.0f / (1.0f + expf(-dotv));
    float vol_w  = 1.0f / (1.0f + expf(-volv / 1000.0f));
    return edge_w * vol_w;
}

// ---------------------------------------------------------------------------
// K0: AB table (1024 x 64), 256 blocks, ~2 us.
// ---------------------------------------------------------------------------
__global__ void ab_kernel(const float* __restrict__ emb,
                          const float* __restrict__ W1,
                          const float* __restrict__ b1,
                          float* __restrict__ ab) {
    int idx = blockIdx.x * 256 + threadIdx.x;   // 0..65535
    int n = idx >> 6, c = idx & 63;
    int half = c >> 5, j = c & 31;
    const float* e = emb + (n << 6);            // wave-uniform row
    const float* w = W1 + (half << 11) + j;
    float acc = half ? 0.0f : b1[j];
    #pragma unroll
    for (int k = 0; k < 64; ++k) acc = fmaf(e[k], w[k << 5], acc);
    ab[idx] = acc;
}

// ---------------------------------------------------------------------------
// K1 (fused, ROUND-1 INTERNALS): 5120 blocks, groups of 5 = {4 adj, 1 nf} so
// the flow-read stream (nf) overlaps the adjacency nt-store drain (adj).
//
// adj block: round-1 adj_dense mechanics — bulk register-cache of all 4096
// edges' (src,dst) for this batch (independent coalesced loads, latency
// hidden under the LDS zero), dense 32 KB priority tile, atomicMax with
// disjoint unique prio ranges (max == last-write-wins), phase-2 winners
// compute w INLINE from the AB table (kills wbuf + the edge kernel), nt
// float4 row streaming.
//
// nf block: round-1 ballot-scan verbatim (VALU-bound, latency-tolerant):
// stage dst row ids in 16 KB of the shared buffer, 64-iter wave scan with
// 8 ballots, ascending-s in-register accumulation (deterministic), butterfly
// L2-normalize, nt row stores.
// ---------------------------------------------------------------------------
__global__ void fused2_kernel(const float* __restrict__ flow,
                              const int* __restrict__ src,
                              const int* __restrict__ dst,
                              const float* __restrict__ vol,
                              const float* __restrict__ ab,
                              const float* __restrict__ W2,
                              const float* __restrict__ b2,
                              float* __restrict__ nf,
                              float* __restrict__ adj) {
    int g = blockIdx.x / 5;
    int r = blockIdx.x - g * 5;
    int t = threadIdx.x;
    __shared__ int D[RPB * NN];              // 32 KB; nf blocks use first 16 KB

    if (r == 4) {
        // ---- node-features block (round-1 ballot scan) ----
        int nb = g;                          // 0..1023
        int row0 = nb << 5;                  // GLOBAL row (b*NN + node)
        int b = row0 >> 10;
        int* sdst = D;                       // 16 KB alias

        const int4* gsrc = (const int4*)(dst + (size_t)b * SS);
        int4* sd4 = (int4*)sdst;
        for (int i = t; i < SS / 4; i += 256) sd4[i] = gsrc[i];
        __syncthreads();

        int wave = t >> 6, lane = t & 63;
        int r0 = row0 + (wave << 3);         // global first row of this wave
        int node0 = r0 & (NN - 1);
        const float* fb = flow + ((size_t)b * SS << 6);

        float acc[8] = {0.f,0.f,0.f,0.f,0.f,0.f,0.f,0.f};
        for (int s0 = 0; s0 < SS; s0 += 64) {
            int d = sdst[s0 + lane];
            #pragma unroll
            for (int j = 0; j < 8; ++j) {
                unsigned long long m = __ballot(d == node0 + j);
                while (m) {                  // ~4 hits per row over whole scan
                    int bit = __ffsll((long long)m) - 1;
                    m &= m - 1;
                    acc[j] += fb[((s0 + bit) << 6) + lane];  // coalesced 256 B
                }
            }
        }
        #pragma unroll
        for (int j = 0; j < 8; ++j) {
            float ss = acc[j] * acc[j];
            #pragma unroll
            for (int off = 32; off > 0; off >>= 1) ss += __shfl_xor(ss, off, 64);
            float v = acc[j] / fmaxf(sqrtf(ss), 1e-12f);
            __builtin_nontemporal_store(v, &nf[((size_t)(r0 + j) << 6) + lane]);
        }
        return;
    }

    // ---- adjacency block (round-1 mechanics + inline w) ----
    int aidx = g * 4 + r;                    // 0..4095
    int b  = aidx >> 7;                      // 128 blocks per batch
    int r0 = (aidx & 127) << 3;              // first of RPB rows

    // bulk register-cache of this thread's 16 edge pairs (independent loads)
    const int* sb = src + (size_t)b * SS;
    const int* db = dst + (size_t)b * SS;
    int svr[16], dvr[16];
    #pragma unroll
    for (int i = 0; i < 16; ++i) {
        svr[i] = sb[t + (i << 8)];
        dvr[i] = db[t + (i << 8)];
    }

    int4* D4 = (int4*)D;
    int4 z; z.x = z.y = z.z = z.w = 0;
    #pragma unroll
    for (int i = 0; i < RPB * NN / 4 / 256; ++i) D4[t + i * 256] = z;
    __syncthreads();

    // phase 1: priority max. prio ranges disjoint & unique -> max == numpy
    // last-write-wins (pass-2 (dst,src) writes always beat pass-1).
    #pragma unroll
    for (int i = 0; i < 16; ++i) {
        int s = t + (i << 8);
        unsigned lr1 = (unsigned)(svr[i] - r0);
        if (lr1 < RPB) atomicMax(&D[(lr1 << 10) + dvr[i]], s + 1);
        unsigned lr2 = (unsigned)(dvr[i] - r0);
        if (lr2 < RPB) atomicMax(&D[(lr2 << 10) + svr[i]], SS + s + 1);
    }
    __syncthreads();

    // phase 2: unique winner per cell computes w inline and deposits bits.
    const float* volb = vol + (size_t)b * SS;
    float b2v = b2[0];
    #pragma unroll
    for (int i = 0; i < 16; ++i) {
        int s = t + (i << 8);
        unsigned lr1 = (unsigned)(svr[i] - r0);
        unsigned lr2 = (unsigned)(dvr[i] - r0);
        if ((lr1 < RPB) | (lr2 < RPB)) {
            float w = edge_weight(ab, W2, b2v, svr[i], dvr[i], volb[s]);
            int wbits = __float_as_int(w);
            if (lr1 < RPB && D[(lr1 << 10) + dvr[i]] == s + 1)
                D[(lr1 << 10) + dvr[i]] = wbits;
            if (lr2 < RPB && D[(lr2 << 10) + svr[i]] == SS + s + 1)
                D[(lr2 << 10) + svr[i]] = wbits;
        }
    }
    __syncthreads();

    // phase 3: stream 8 full rows (32 KB contiguous) out, nt float4 stores
    const v4i* Df = (const v4i*)D;
    v4i* out = (v4i*)(adj + ((size_t)b * NN + r0) * NN);
    #pragma unroll
    for (int i = 0; i < RPB * NN / 4 / 256; ++i)
        __builtin_nontemporal_store(Df[t + i * 256], &out[t + i * 256]);
}

// ===========================================================================
// Fallback path (round-1 proven kernels) — used only if workspace cannot hold
// the 256 KB AB table (then ab must live in the adj tail, which is only safe
// with the fully sequential 3-kernel pipeline).
// ===========================================================================
__global__ void nf_edge_kernel(const float* __restrict__ flow,
                               const int* __restrict__ src,
                               const int* __restrict__ dst,
                               const float* __restrict__ vol,
                               const float* __restrict__ ab,
                               const float* __restrict__ W2,
                               const float* __restrict__ b2,
                               float* __restrict__ nf,
                               float* __restrict__ wout) {
    if (blockIdx.x < EDGE_BLOCKS) {
        int i = blockIdx.x * 256 + threadIdx.x;
        float w = edge_weight(ab, W2, b2[0], src[i], dst[i], vol[i]);
        wout[i] = w;
        return;
    }
    int nb = blockIdx.x - EDGE_BLOCKS;
    int row0 = nb << 5;
    int b = row0 >> 10;
    __shared__ int sdst[SS];
    const int4* g = (const int4*)(dst + (size_t)b * SS);
    int4* sd4 = (int4*)sdst;
    for (int t = threadIdx.x; t < SS / 4; t += 256) sd4[t] = g[t];
    __syncthreads();
    int wave = threadIdx.x >> 6, lane = threadIdx.x & 63;
    int r0 = row0 + (wave << 3);
    int node0 = r0 & (NN - 1);
    const float* fb = flow + ((size_t)b * SS << 6);
    float acc[8] = {0.f,0.f,0.f,0.f,0.f,0.f,0.f,0.f};
    for (int s0 = 0; s0 < SS; s0 += 64) {
        int d = sdst[s0 + lane];
        #pragma unroll
        for (int j = 0; j < 8; ++j) {
            unsigned long long m = __ballot(d == node0 + j);
            while (m) {
                int bit = __ffsll((long long)m) - 1;
                m &= m - 1;
                acc[j] += fb[((s0 + bit) << 6) + lane];
            }
        }
    }
    #pragma unroll
    for (int j = 0; j < 8; ++j) {
        float ss = acc[j] * acc[j];
        #pragma unroll
        for (int off = 32; off > 0; off >>= 1) ss += __shfl_xor(ss, off, 64);
        float v = acc[j] / fmaxf(sqrtf(ss), 1e-12f);
        __builtin_nontemporal_store(v, &nf[((size_t)(r0 + j) << 6) + lane]);
    }
}

__global__ void adj_dense_kernel(const int* __restrict__ src,
                                 const int* __restrict__ dst,
                                 const float* __restrict__ wbuf,
                                 float* __restrict__ adj) {
    int b  = blockIdx.x >> 7;
    int r0 = (blockIdx.x & 127) << 3;
    int tid = threadIdx.x;
    __shared__ int D[RPB * NN];
    const int* sb = src + (size_t)b * SS;
    const int* db = dst + (size_t)b * SS;
    int svr[16], dvr[16];
    #pragma unroll
    for (int i = 0; i < 16; ++i) { svr[i] = sb[tid + (i << 8)]; dvr[i] = db[tid + (i << 8)]; }
    int4* D4 = (int4*)D;
    int4 z; z.x = z.y = z.z = z.w = 0;
    #pragma unroll
    for (int i = 0; i < RPB * NN / 4 / 256; ++i) D4[tid + i * 256] = z;
    __syncthreads();
    #pragma unroll
    for (int i = 0; i < 16; ++i) {
        int s = tid + (i << 8);
        unsigned lr1 = (unsigned)(svr[i] - r0);
        if (lr1 < RPB) atomicMax(&D[(lr1 << 10) + dvr[i]], s + 1);
        unsigned lr2 = (unsigned)(dvr[i] - r0);
        if (lr2 < RPB) atomicMax(&D[(lr2 << 10) + svr[i]], SS + s + 1);
    }
    __syncthreads();
    const float* wb = wbuf + (size_t)b * SS;
    #pragma unroll
    for (int i = 0; i < 16; ++i) {
        int s = tid + (i << 8);
        unsigned lr1 = (unsigned)(svr[i] - r0);
        unsigned lr2 = (unsigned)(dvr[i] - r0);
        if ((lr1 < RPB) | (lr2 < RPB)) {
            int wbits = __float_as_int(wb[s]);
            if (lr1 < RPB && D[(lr1 << 10) + dvr[i]] == s + 1) D[(lr1 << 10) + dvr[i]] = wbits;
            if (lr2 < RPB && D[(lr2 << 10) + svr[i]] == SS + s + 1) D[(lr2 << 10) + svr[i]] = wbits;
        }
    }
    __syncthreads();
    const v4i* Df = (const v4i*)D;
    v4i* out = (v4i*)(adj + ((size_t)b * NN + r0) * NN);
    #pragma unroll
    for (int i = 0; i < RPB * NN / 4 / 256; ++i)
        __builtin_nontemporal_store(Df[tid + i * 256], &out[tid + i * 256]);
}

extern "C" void kernel_launch(void* const* d_in, const int* in_sizes, int n_in,
                              void* d_out, int out_size, void* d_ws, size_t ws_size,
                              hipStream_t stream) {
    const float* flow = (const float*)d_in[0];   // (B,S,64)
    const int*   src  = (const int*)d_in[1];     // (B,S)
    const int*   dst  = (const int*)d_in[2];     // (B,S)
    const float* vol  = (const float*)d_in[3];   // (B,S)
    const float* emb  = (const float*)d_in[4];   // (1024,64)
    const float* W1   = (const float*)d_in[5];   // (128,32)
    const float* b1   = (const float*)d_in[6];   // (32,)
    const float* W2   = (const float*)d_in[7];   // (32,1)
    const float* b2   = (const float*)d_in[8];   // (1,)

    float* nf  = (float*)d_out;                         // (B,N,64)
    float* adj = nf + (size_t)BB * NN * FEAT_;          // (B,N,N)

    if (ws_size >= (size_t)NN * 64 * sizeof(float)) {
        // main path: AB table in workspace, 2 launches total
        float* ab = (float*)d_ws;
        ab_kernel<<<(NN * 64) / 256, 256, 0, stream>>>(emb, W1, b1, ab);
        fused2_kernel<<<5 * BB * (NN / RPB) / 4, 256, 0, stream>>>(
            flow, src, dst, vol, ab, W2, b2, nf, adj);
        return;
    }

    // fallback: round-1 proven sequential 3-kernel path (ab may live in the
    // adj tail because nf_edge completes before adj_dense overwrites it)
    float* wbuf = (float*)d_ws;                         // (B,S)
    float* ab;
    if (ws_size >= (size_t)(BB * SS + NN * 64) * sizeof(float))
        ab = wbuf + (size_t)BB * SS;
    else
        ab = adj + (size_t)BB * NN * NN - (size_t)NN * 64;
    ab_kernel<<<(NN * 64) / 256, 256, 0, stream>>>(emb, W1, b1, ab);
    nf_edge_kernel<<<EDGE_BLOCKS + NF_BLOCKS, 256, 0, stream>>>(
        flow, src, dst, vol, ab, W2, b2, nf, wbuf);
    adj_dense_kernel<<<BB * (NN / RPB), 256, 0, stream>>>(src, dst, wbuf, adj);
}

// Round 5
// 224.083 us; speedup vs baseline: 1.3364x; 1.3364x over previous
//
#include <hip/hip_runtime.h>
#include <cstdint>
#include <cstddef>

// Problem constants (match reference setup_inputs)
#define BB 32
#define SS 4096          // 2^12
#define FEAT_ 64
#define HID_ 32
#define NN 1024          // MAX_NODES
#define RPB 8            // adjacency rows per block (dense LDS tile = 32 KB)

#define EDGE_BLOCKS ((BB * SS) / 256)   // 512 edge blocks
#define NF_BLOCKS   ((BB * NN) / 32)    // 1024 nf blocks (32 rows each)

typedef int v4i __attribute__((ext_vector_type(4)));

// ---------------------------------------------------------------------------
// Edge weight from the factored MLP.
//   AB[n][0:32]  = emb[n] @ W1[0:64] + b1     (A half)
//   AB[n][32:64] = emb[n] @ W1[64:128]        (B half)
// Float expression identical to the round-1 edge phase -> bit-identical w.
// ---------------------------------------------------------------------------
__device__ __forceinline__ float edge_weight(const float* __restrict__ ab,
                                             const float* __restrict__ W2,
                                             float b2v, int src_n, int dst_n,
                                             float volv) {
    const float4* As = (const float4*)(ab + (src_n << 6));
    const float4* Bd = (const float4*)(ab + (dst_n << 6) + HID_);
    float dotv = b2v;
    #pragma unroll
    for (int q = 0; q < 8; ++q) {
        float4 a  = As[q];
        float4 bv = Bd[q];
        float4 wv = *(const float4*)(W2 + (q << 2));
        dotv += fmaxf(a.x + bv.x, 0.0f) * wv.x;
        dotv += fmaxf(a.y + bv.y, 0.0f) * wv.y;
        dotv += fmaxf(a.z + bv.z, 0.0f) * wv.z;
        dotv += fmaxf(a.w + bv.w, 0.0f) * wv.w;
    }
    float edge_w = 1.0f / (1.0f + expf(-dotv));
    float vol_w  = 1.0f / (1.0f + expf(-volv / 1000.0f));
    return edge_w * vol_w;
}

// ---------------------------------------------------------------------------
// K0: AB table (1024 x 64), 256 blocks, ~2 us.
// ---------------------------------------------------------------------------
__global__ void ab_kernel(const float* __restrict__ emb,
                          const float* __restrict__ W1,
                          const float* __restrict__ b1,
                          float* __restrict__ ab) {
    int idx = blockIdx.x * 256 + threadIdx.x;   // 0..65535
    int n = idx >> 6, c = idx & 63;
    int half = c >> 5, j = c & 31;
    const float* e = emb + (n << 6);            // wave-uniform row
    const float* w = W1 + (half << 11) + j;
    float acc = half ? 0.0f : b1[j];
    #pragma unroll
    for (int k = 0; k < 64; ++k) acc = fmaf(e[k], w[k << 5], acc);
    ab[idx] = acc;
}

// ---------------------------------------------------------------------------
// K1: grid-split edge combine + node features (ROUND-1 STRUCTURE — the
// measured-best config; both fused variants regressed 27-74 us).
//
// blocks [0,512): per-edge w from AB table -> wbuf. Trivial (~2-3 us).
//
// blocks [512,1536): node features. One block = 32 rows (4 waves x 8 rows) of
// one batch; dst ids staged once in 16 KB LDS.
// Scan change vs round-1: ONE range-ballot per 64-lane chunk instead of 8
// per-row ballots (8x less scan VALU). A hit lane's (d - node0) is pulled
// with __shfl -> wave-UNIFORM j -> cheap scalar-branch dispatch into 8 named
// accumulators. Per-row accumulation order remains ascending-s (outer s0
// ascending, ballot bits ascending) -> bit-identical to round-1 output.
// ---------------------------------------------------------------------------
__global__ void nf_edge_kernel(const float* __restrict__ flow,
                               const int* __restrict__ src,
                               const int* __restrict__ dst,
                               const float* __restrict__ vol,
                               const float* __restrict__ ab,
                               const float* __restrict__ W2,
                               const float* __restrict__ b2,
                               float* __restrict__ nf,
                               float* __restrict__ wout) {
    if (blockIdx.x < EDGE_BLOCKS) {
        int i = blockIdx.x * 256 + threadIdx.x;
        wout[i] = edge_weight(ab, W2, b2[0], src[i], dst[i], vol[i]);
        return;
    }

    int nb = blockIdx.x - EDGE_BLOCKS;       // 0..1023
    int row0 = nb << 5;                      // GLOBAL row (b*NN + node)
    int b = row0 >> 10;
    __shared__ int sdst[SS];                 // 16 KB

    const int4* g = (const int4*)(dst + (size_t)b * SS);
    int4* sd4 = (int4*)sdst;
    for (int t = threadIdx.x; t < SS / 4; t += 256) sd4[t] = g[t];
    __syncthreads();

    int wave = threadIdx.x >> 6, lane = threadIdx.x & 63;
    int r0 = row0 + (wave << 3);             // global first row of this wave
    int node0 = r0 & (NN - 1);
    const float* fb = flow + ((size_t)b * SS << 6);

    float a0 = 0.f, a1 = 0.f, a2 = 0.f, a3 = 0.f;
    float a4 = 0.f, a5 = 0.f, a6 = 0.f, a7 = 0.f;
    for (int s0 = 0; s0 < SS; s0 += 64) {
        unsigned diff = (unsigned)(sdst[s0 + lane] - node0);
        unsigned long long m = __ballot(diff < 8u);   // ~0.5 hits/iter expected
        while (m) {
            int bit = __ffsll((long long)m) - 1;
            m &= m - 1;
            int j = __shfl((int)diff, bit, 64);       // wave-uniform row offset
            float v = fb[((s0 + bit) << 6) + lane];   // coalesced 256 B row
            if      (j == 0) a0 += v;
            else if (j == 1) a1 += v;
            else if (j == 2) a2 += v;
            else if (j == 3) a3 += v;
            else if (j == 4) a4 += v;
            else if (j == 5) a5 += v;
            else if (j == 6) a6 += v;
            else             a7 += v;
        }
    }

    float accs[8] = {a0, a1, a2, a3, a4, a5, a6, a7};
    #pragma unroll
    for (int j = 0; j < 8; ++j) {
        float ss = accs[j] * accs[j];
        #pragma unroll
        for (int off = 32; off > 0; off >>= 1) ss += __shfl_xor(ss, off, 64);
        float v = accs[j] / fmaxf(sqrtf(ss), 1e-12f);
        __builtin_nontemporal_store(v, &nf[((size_t)(r0 + j) << 6) + lane]);
    }
}

// ---------------------------------------------------------------------------
// K2: adjacency via dense LDS priority tile (round-1 verbatim — measured at
// ~store roofline). Block owns RPB=8 rows of one batch:
//   phase 0: zero D (untouched cells -> 0.0f for free)
//   phase 1: matched edges atomicMax prio into D; prio = s+1 (cell src,dst) /
//            S+s+1 (cell dst,src); ranges disjoint & unique -> max ==
//            numpy last-write-wins
//   phase 2: unique max-prio winner replaces prio with w bits from wbuf
//   phase 3: stream D out as NON-TEMPORAL float4 (bypass L2 write-allocate)
// src/dst register-cached across phases; global edge reads once per block.
// ---------------------------------------------------------------------------
__global__ void adj_dense_kernel(const int* __restrict__ src,
                                 const int* __restrict__ dst,
                                 const float* __restrict__ wbuf,
                                 float* __restrict__ adj) {
    int b  = blockIdx.x >> 7;                 // 128 blocks per batch
    int r0 = (blockIdx.x & 127) << 3;         // first of RPB rows
    int tid = threadIdx.x;

    __shared__ int D[RPB * NN];               // 32 KB dense tile

    const int* sb = src + (size_t)b * SS;
    const int* db = dst + (size_t)b * SS;
    int svr[16], dvr[16];
    #pragma unroll
    for (int i = 0; i < 16; ++i) {
        svr[i] = sb[tid + (i << 8)];
        dvr[i] = db[tid + (i << 8)];
    }

    int4* D4 = (int4*)D;
    int4 z; z.x = z.y = z.z = z.w = 0;
    #pragma unroll
    for (int i = 0; i < RPB * NN / 4 / 256; ++i) D4[tid + i * 256] = z;
    __syncthreads();

    #pragma unroll
    for (int i = 0; i < 16; ++i) {
        int s = tid + (i << 8);
        unsigned lr1 = (unsigned)(svr[i] - r0);
        if (lr1 < RPB) atomicMax(&D[(lr1 << 10) + dvr[i]], s + 1);
        unsigned lr2 = (unsigned)(dvr[i] - r0);
        if (lr2 < RPB) atomicMax(&D[(lr2 << 10) + svr[i]], SS + s + 1);
    }
    __syncthreads();

    const float* wb = wbuf + (size_t)b * SS;
    #pragma unroll
    for (int i = 0; i < 16; ++i) {
        int s = tid + (i << 8);
        unsigned lr1 = (unsigned)(svr[i] - r0);
        unsigned lr2 = (unsigned)(dvr[i] - r0);
        if ((lr1 < RPB) | (lr2 < RPB)) {
            int wbits = __float_as_int(wb[s]);
            if (lr1 < RPB && D[(lr1 << 10) + dvr[i]] == s + 1)
                D[(lr1 << 10) + dvr[i]] = wbits;
            if (lr2 < RPB && D[(lr2 << 10) + svr[i]] == SS + s + 1)
                D[(lr2 << 10) + svr[i]] = wbits;
        }
    }
    __syncthreads();

    const v4i* Df = (const v4i*)D;
    v4i* out = (v4i*)(adj + ((size_t)b * NN + r0) * NN);
    #pragma unroll
    for (int i = 0; i < RPB * NN / 4 / 256; ++i)
        __builtin_nontemporal_store(Df[tid + i * 256], &out[tid + i * 256]);
}

extern "C" void kernel_launch(void* const* d_in, const int* in_sizes, int n_in,
                              void* d_out, int out_size, void* d_ws, size_t ws_size,
                              hipStream_t stream) {
    const float* flow = (const float*)d_in[0];   // (B,S,64)
    const int*   src  = (const int*)d_in[1];     // (B,S)
    const int*   dst  = (const int*)d_in[2];     // (B,S)
    const float* vol  = (const float*)d_in[3];   // (B,S)
    const float* emb  = (const float*)d_in[4];   // (1024,64)
    const float* W1   = (const float*)d_in[5];   // (128,32)
    const float* b1   = (const float*)d_in[6];   // (32,)
    const float* W2   = (const float*)d_in[7];   // (32,1)
    const float* b2   = (const float*)d_in[8];   // (1,)

    float* nf  = (float*)d_out;                         // (B,N,64)
    float* adj = nf + (size_t)BB * NN * FEAT_;          // (B,N,N)
    float* wbuf = (float*)d_ws;                         // (B,S) edge weights

    // 256 KB AB table: prefer workspace after wbuf; else borrow the tail of
    // the adjacency output (nf_edge completes before adj_dense overwrites it,
    // same stream -> safe with this sequential pipeline).
    float* ab;
    if (ws_size >= (size_t)(BB * SS + NN * 64) * sizeof(float))
        ab = wbuf + (size_t)BB * SS;
    else
        ab = adj + (size_t)BB * NN * NN - (size_t)NN * 64;

    // Every output byte is written exactly once by the kernels below —
    // no memset of d_out at all.
    ab_kernel<<<(NN * 64) / 256, 256, 0, stream>>>(emb, W1, b1, ab);
    nf_edge_kernel<<<EDGE_BLOCKS + NF_BLOCKS, 256, 0, stream>>>(
        flow, src, dst, vol, ab, W2, b2, nf, wbuf);
    adj_dense_kernel<<<BB * (NN / RPB), 256, 0, stream>>>(src, dst, wbuf, adj);
}